// Round 17
// baseline (507.005 us; speedup 1.0000x reference)
//
#include <hip/hip_runtime.h>
#include <hip/hip_bf16.h>
#include <math.h>

#define NN 50000
#define EE 1600000
#define DD 128
#define HH 4
#define NSTEP 3
#define NEG 0.2f
#define BM 32     // gemm rows per block
#define NPB 8     // nodes per block in node_k3
#define CAPN 128  // per-node LDS stash (= 4 segments x 32)
#define NPART 4   // sub-counters per node (cuts same-address atomic collisions 4x)
#define SEGC 32   // capacity per segment (Poisson(8): P(>32) ~ 1e-11)

typedef unsigned short ushort8v __attribute__((ext_vector_type(8)));
typedef float float4v __attribute__((ext_vector_type(4)));

__device__ __forceinline__ float leaky(float v) { return v >= 0.0f ? v : NEG * v; }

__device__ __forceinline__ unsigned short bfu(float f) {
    __hip_bfloat16 b = __float2bfloat16(f);   // RNE
    return *reinterpret_cast<unsigned short*>(&b);
}
__device__ __forceinline__ float ubf(unsigned short u) {
    return __uint_as_float(((unsigned int)u) << 16);
}

// ---------------- fused h = x@W (bf16 out) and alpha dots ----------------
// as_ -> [N] float4 ; nd -> [N][3] float4, slot 0 = ad (slots 1,2 filled by node_k3)
__global__ __launch_bounds__(256) void gemm_k2(const float* __restrict__ X,
                                               const float* __restrict__ W,
                                               const float* __restrict__ a_src,
                                               const float* __restrict__ a_dst,
                                               unsigned short* __restrict__ Hb,
                                               float* __restrict__ as_,
                                               float4* __restrict__ nd) {
    __shared__ float xs[BM][132];
    const int tid  = threadIdx.x;
    const int tcol = tid & 31;
    const int trow = tid >> 5;
    const int row0 = blockIdx.x * BM;

    #pragma unroll
    for (int i = 0; i < 4; ++i) {
        const int l  = tid + 256 * i;
        const int r  = l >> 5;
        const int c4 = l & 31;
        float4 v = {0.f, 0.f, 0.f, 0.f};
        if (row0 + r < NN) v = ((const float4*)(X + (size_t)(row0 + r) * DD))[c4];
        *(float4*)&xs[r][c4 * 4] = v;
    }
    __syncthreads();

    const float4* __restrict__ W4 = (const float4*)W;
    float4 acc0 = {0,0,0,0}, acc1 = {0,0,0,0}, acc2 = {0,0,0,0}, acc3 = {0,0,0,0};

    for (int k = 0; k < DD; k += 4) {
        float4 wv0 = W4[(k + 0) * 32 + tcol];
        float4 wv1 = W4[(k + 1) * 32 + tcol];
        float4 wv2 = W4[(k + 2) * 32 + tcol];
        float4 wv3 = W4[(k + 3) * 32 + tcol];
        float4 xv0 = *(const float4*)&xs[4 * trow + 0][k];
        float4 xv1 = *(const float4*)&xs[4 * trow + 1][k];
        float4 xv2 = *(const float4*)&xs[4 * trow + 2][k];
        float4 xv3 = *(const float4*)&xs[4 * trow + 3][k];
        #define GSTEP(ACC, XV) \
            ACC.x += XV.x * wv0.x; ACC.y += XV.x * wv0.y; ACC.z += XV.x * wv0.z; ACC.w += XV.x * wv0.w; \
            ACC.x += XV.y * wv1.x; ACC.y += XV.y * wv1.y; ACC.z += XV.y * wv1.z; ACC.w += XV.y * wv1.w; \
            ACC.x += XV.z * wv2.x; ACC.y += XV.z * wv2.y; ACC.z += XV.z * wv2.z; ACC.w += XV.z * wv2.w; \
            ACC.x += XV.w * wv3.x; ACC.y += XV.w * wv3.y; ACC.z += XV.w * wv3.z; ACC.w += XV.w * wv3.w;
        GSTEP(acc0, xv0) GSTEP(acc1, xv1) GSTEP(acc2, xv2) GSTEP(acc3, xv3)
        #undef GSTEP
    }

    const float4 asv = ((const float4*)a_src)[tcol];
    const float4 adv = ((const float4*)a_dst)[tcol];
    float ps0 = acc0.x*asv.x + acc0.y*asv.y + acc0.z*asv.z + acc0.w*asv.w;
    float ps1 = acc1.x*asv.x + acc1.y*asv.y + acc1.z*asv.z + acc1.w*asv.w;
    float ps2 = acc2.x*asv.x + acc2.y*asv.y + acc2.z*asv.z + acc2.w*asv.w;
    float ps3 = acc3.x*asv.x + acc3.y*asv.y + acc3.z*asv.z + acc3.w*asv.w;
    float pd0 = acc0.x*adv.x + acc0.y*adv.y + acc0.z*adv.z + acc0.w*adv.w;
    float pd1 = acc1.x*adv.x + acc1.y*adv.y + acc1.z*adv.z + acc1.w*adv.w;
    float pd2 = acc2.x*adv.x + acc2.y*adv.y + acc2.z*adv.z + acc2.w*adv.w;
    float pd3 = acc3.x*adv.x + acc3.y*adv.y + acc3.z*adv.z + acc3.w*adv.w;
    #pragma unroll
    for (int off = 1; off < 8; off <<= 1) {
        ps0 += __shfl_xor(ps0, off); ps1 += __shfl_xor(ps1, off);
        ps2 += __shfl_xor(ps2, off); ps3 += __shfl_xor(ps3, off);
        pd0 += __shfl_xor(pd0, off); pd1 += __shfl_xor(pd1, off);
        pd2 += __shfl_xor(pd2, off); pd3 += __shfl_xor(pd3, off);
    }

    #pragma unroll
    for (int i = 0; i < 4; ++i) {
        const int row = row0 + 4 * trow + i;
        if (row >= NN) break;
        const float4 a = (i == 0) ? acc0 : (i == 1) ? acc1 : (i == 2) ? acc2 : acc3;
        ushort4 p;
        p.x = bfu(a.x); p.y = bfu(a.y); p.z = bfu(a.z); p.w = bfu(a.w);
        *(ushort4*)&Hb[(size_t)row * DD + 4 * tcol] = p;
    }
    if ((tcol & 7) == 0) {
        const int head = tcol >> 3;
        #pragma unroll
        for (int i = 0; i < 4; ++i) {
            const int row = row0 + 4 * trow + i;
            if (row >= NN) break;
            const float ps = (i == 0) ? ps0 : (i == 1) ? ps1 : (i == 2) ? ps2 : ps3;
            const float pd = (i == 0) ? pd0 : (i == 1) ? pd1 : (i == 2) ? pd2 : pd3;
            as_[(size_t)row * HH + head] = ps;
            ((float*)(nd + (size_t)row * 3))[head] = pd;
        }
    }
}

// ---------------- partitioned padded-CSR build: ONE atomic pass ----------------
__global__ __launch_bounds__(256) void zero_k(int* __restrict__ p, int n) {
    const int i = blockIdx.x * 256 + threadIdx.x;
    if (i < n) p[i] = 0;
}

// counter domain split NPART ways per node: cursor[d*NPART + (e&3)]
__global__ __launch_bounds__(256) void scat_k(const int* __restrict__ ei,
                                              int* __restrict__ cursor,
                                              unsigned short* __restrict__ csr) {
    const int e = blockIdx.x * 256 + threadIdx.x;
    if (e >= EE) return;
    const int s = ei[e], d = ei[EE + e];
    const int c = d * NPART + (e & (NPART - 1));
    const int pos = atomicAdd(&cursor[c], 1);
    if (pos < SEGC) csr[(size_t)c * SEGC + pos] = (unsigned short)s;
}

// ---------------- per-destination softmax stats + aggregation ----------------
// 8 nodes/block, 32 lanes/node, no __syncthreads. Writes nd slots 1,2 + xout.
__global__ __launch_bounds__(256) void node_k3(const int* __restrict__ cursor,
                                               const unsigned short* __restrict__ csr,
                                               const float* __restrict__ as_,
                                               float4* __restrict__ nd,    // [N][3]: ad, m, inv
                                               const unsigned short* __restrict__ Hb,
                                               const float* __restrict__ xprev,
                                               float* __restrict__ xout) {
    __shared__ int    src_l[NPB][CAPN];
    __shared__ float4 exp_l[NPB][CAPN];

    const int tid  = threadIdx.x;
    const int nl   = tid >> 5;
    const int lane = tid & 31;
    const int n    = blockIdx.x * NPB + nl;

    const int cbase = n * NPART;
    int degs[NPART];
    int deg = 0;
    #pragma unroll
    for (int p = 0; p < NPART; ++p) {
        int dp = cursor[cbase + p];
        if (dp > SEGC) dp = SEGC;
        degs[p] = dp;
        deg += dp;
    }

    if (deg == 0) {
        ((float4*)(xout + (size_t)n * DD))[lane] = ((const float4*)(xprev + (size_t)n * DD))[lane];
        return;
    }

    const float4 adv = nd[(size_t)n * 3];

    // Phase A: per-segment logits, compacted into LDS stash; group max
    float4 mx = {-INFINITY, -INFINITY, -INFINITY, -INFINITY};
    int off = 0;
    #pragma unroll
    for (int p = 0; p < NPART; ++p) {
        if (lane < degs[p]) {
            const int s = (int)csr[(size_t)(cbase + p) * SEGC + lane];
            const float4 av = *(const float4*)(as_ + (size_t)s * HH);
            float4 l;
            l.x = leaky(av.x + adv.x); l.y = leaky(av.y + adv.y);
            l.z = leaky(av.z + adv.z); l.w = leaky(av.w + adv.w);
            src_l[nl][off + lane] = s; exp_l[nl][off + lane] = l;
            mx.x = fmaxf(mx.x, l.x); mx.y = fmaxf(mx.y, l.y);
            mx.z = fmaxf(mx.z, l.z); mx.w = fmaxf(mx.w, l.w);
        }
        off += degs[p];
    }
    #pragma unroll
    for (int o = 1; o < 32; o <<= 1) {
        mx.x = fmaxf(mx.x, __shfl_xor(mx.x, o));
        mx.y = fmaxf(mx.y, __shfl_xor(mx.y, o));
        mx.z = fmaxf(mx.z, __shfl_xor(mx.z, o));
        mx.w = fmaxf(mx.w, __shfl_xor(mx.w, o));
    }

    // Phase B: exp (stash), group denom  (compact 0..deg)
    float4 ds = {0.f, 0.f, 0.f, 0.f};
    for (int j = lane; j < deg; j += 32) {
        const float4 l = exp_l[nl][j];
        float4 e4;
        e4.x = expf(l.x - mx.x); e4.y = expf(l.y - mx.y);
        e4.z = expf(l.z - mx.z); e4.w = expf(l.w - mx.w);
        exp_l[nl][j] = e4;
        ds.x += e4.x; ds.y += e4.y; ds.z += e4.z; ds.w += e4.w;
    }
    #pragma unroll
    for (int o = 1; o < 32; o <<= 1) {
        ds.x += __shfl_xor(ds.x, o); ds.y += __shfl_xor(ds.y, o);
        ds.z += __shfl_xor(ds.z, o); ds.w += __shfl_xor(ds.w, o);
    }
    float4 inv;
    inv.x = 1.0f / (ds.x + 1e-16f); inv.y = 1.0f / (ds.y + 1e-16f);
    inv.z = 1.0f / (ds.z + 1e-16f); inv.w = 1.0f / (ds.w + 1e-16f);

    if (lane == 0) {
        nd[(size_t)n * 3 + 1] = mx;
        nd[(size_t)n * 3 + 2] = inv;
    }

    // Phase C: aggregation — 2 edges/iter, 16 lanes/edge, 16B loads.
    const int esel = lane >> 4;
    const int sub  = lane & 15;
    const int hsel = sub >> 2;
    const float invh = (hsel == 0) ? inv.x : (hsel == 1) ? inv.y : (hsel == 2) ? inv.z : inv.w;
    float4 aclo = {0.f, 0.f, 0.f, 0.f};
    float4 achi = {0.f, 0.f, 0.f, 0.f};
    int j0 = 0;
    #pragma unroll 2
    for (; j0 + 2 <= deg; j0 += 2) {
        const int j = j0 + esel;
        const int s = src_l[nl][j];
        const float a = ((const float*)&exp_l[nl][j])[hsel] * invh;
        const ushort8v hv = *(const ushort8v*)&Hb[(size_t)s * DD + 8 * sub];
        aclo.x += ubf(hv[0]) * a; aclo.y += ubf(hv[1]) * a;
        aclo.z += ubf(hv[2]) * a; aclo.w += ubf(hv[3]) * a;
        achi.x += ubf(hv[4]) * a; achi.y += ubf(hv[5]) * a;
        achi.z += ubf(hv[6]) * a; achi.w += ubf(hv[7]) * a;
    }
    if (j0 < deg && esel == 0) {   // odd tail: esel==0 lanes only
        const int j = j0;
        const int s = src_l[nl][j];
        const float a = ((const float*)&exp_l[nl][j])[hsel] * invh;
        const ushort8v hv = *(const ushort8v*)&Hb[(size_t)s * DD + 8 * sub];
        aclo.x += ubf(hv[0]) * a; aclo.y += ubf(hv[1]) * a;
        aclo.z += ubf(hv[2]) * a; aclo.w += ubf(hv[3]) * a;
        achi.x += ubf(hv[4]) * a; achi.y += ubf(hv[5]) * a;
        achi.z += ubf(hv[6]) * a; achi.w += ubf(hv[7]) * a;
    }
    aclo.x += __shfl_xor(aclo.x, 16); aclo.y += __shfl_xor(aclo.y, 16);
    aclo.z += __shfl_xor(aclo.z, 16); aclo.w += __shfl_xor(aclo.w, 16);
    achi.x += __shfl_xor(achi.x, 16); achi.y += __shfl_xor(achi.y, 16);
    achi.z += __shfl_xor(achi.z, 16); achi.w += __shfl_xor(achi.w, 16);
    const float4 mine = (esel == 0) ? aclo : achi;
    const int fidx = 2 * sub + esel;
    const float4 xv = ((const float4*)(xprev + (size_t)n * DD))[fidx];
    float4 o;
    o.x = xv.x + mine.x; o.y = xv.y + mine.y; o.z = xv.z + mine.z; o.w = xv.w + mine.w;
    ((float4*)(xout + (size_t)n * DD))[fidx] = o;
}

// ---------------- edge-ordered rel + attn; one step per blockIdx.y ----------------
__global__ __launch_bounds__(256) void edgeattn3_k(const int* __restrict__ ei,
                                                   const float* __restrict__ as3,
                                                   const float4* __restrict__ nd3,
                                                   float* __restrict__ rel_out,
                                                   float* __restrict__ attn_out) {
    const int e = blockIdx.x * 256 + threadIdx.x;
    if (e >= EE) return;
    const int st = blockIdx.y;
    const int s = __builtin_nontemporal_load(ei + e);
    const int d = __builtin_nontemporal_load(ei + EE + e);
    const float4 av = *(const float4*)(as3 + ((size_t)st * NN + s) * HH);
    const float4* ndp = nd3 + ((size_t)st * NN + d) * 3;
    const float4 dv = ndp[0];
    const float4 mm = ndp[1];
    const float4 iv = ndp[2];
    float4v l;
    l.x = leaky(av.x + dv.x); l.y = leaky(av.y + dv.y);
    l.z = leaky(av.z + dv.z); l.w = leaky(av.w + dv.w);
    __builtin_nontemporal_store(l, (float4v*)(rel_out + ((size_t)st * EE + e) * HH));
    float4v a;
    a.x = expf(l.x - mm.x) * iv.x; a.y = expf(l.y - mm.y) * iv.y;
    a.z = expf(l.z - mm.z) * iv.z; a.w = expf(l.w - mm.w) * iv.w;
    __builtin_nontemporal_store(a, (float4v*)(attn_out + ((size_t)st * EE + e) * HH));
}

extern "C" void kernel_launch(void* const* d_in, const int* in_sizes, int n_in,
                              void* d_out, int out_size, void* d_ws, size_t ws_size,
                              hipStream_t stream) {
    const float* x     = (const float*)d_in[0];
    const int*   ei    = (const int*)d_in[1];
    const float* W     = (const float*)d_in[2];
    const float* a_src = (const float*)d_in[3];
    const float* a_dst = (const float*)d_in[4];

    float* xs_out   = (float*)d_out;                         // [3,N,128]
    float* attn_out = xs_out + (size_t)NSTEP * NN * DD;      // [3,E,4]
    float* rel_out  = attn_out + (size_t)NSTEP * EE * HH;    // [3,E,4]

    unsigned short* hb = (unsigned short*)d_ws;              // N*128 bf16          (12.8 MB)
    float*  as3   = (float*)(hb + (size_t)NN * DD);          // [3][N][4]           (2.4 MB)
    float4* nd3   = (float4*)(as3 + (size_t)NSTEP * NN * HH);// [3][N][3] ad,m,inv  (7.2 MB)
    int*    cursor = (int*)(nd3 + (size_t)NSTEP * NN * 3);   // N*NPART             (0.8 MB)
    unsigned short* csr = (unsigned short*)(cursor + (size_t)NN * NPART); // N*NPART*SEGC ushort (12.8 MB)

    // partitioned padded-CSR build: zero cursors + ONE atomic scatter pass
    zero_k<<<(NN * NPART + 255) / 256, 256, 0, stream>>>(cursor, NN * NPART);
    scat_k<<<(EE + 255) / 256, 256, 0, stream>>>(ei, cursor, csr);

    const float* xprev = x;
    for (int s = 0; s < NSTEP; ++s) {
        float* xs_s = xs_out + (size_t)s * NN * DD;
        float* as_  = as3 + (size_t)s * NN * HH;
        float4* nd  = nd3 + (size_t)s * NN * 3;

        gemm_k2<<<(NN + BM - 1) / BM, 256, 0, stream>>>(xprev, W, a_src, a_dst, hb, as_, nd);
        node_k3<<<NN / NPB, 256, 0, stream>>>(cursor, csr, as_, nd, hb, xprev, xs_s);
        xprev = xs_s;
    }
    dim3 eg((EE + 255) / 256, NSTEP);
    edgeattn3_k<<<eg, 256, 0, stream>>>(ei, as3, nd3, rel_out, attn_out);
}

// Round 18
// 477.246 us; speedup vs baseline: 1.0624x; 1.0624x over previous
//
#include <hip/hip_runtime.h>
#include <hip/hip_bf16.h>
#include <math.h>

#define NN 50000
#define EE 1600000
#define DD 128
#define HH 4
#define NSTEP 3
#define NEG 0.2f
#define BM 32      // gemm rows per block
#define NPB 8      // nodes per block in node_k3
#define CAPN 128   // per-node LDS stash (deg Poisson(32); clamp for safety)
#define NBUCK 196  // coarse buckets: d>>8, d<50000
#define BUCKCAP 9216  // padded bucket capacity (mean 8192, +11 sigma)
#define P1CH 16384    // edges per p1 block
#define NB1 ((EE + P1CH - 1) / P1CH)   // 98

typedef unsigned short ushort8v __attribute__((ext_vector_type(8)));
typedef float float4v __attribute__((ext_vector_type(4)));

__device__ __forceinline__ float leaky(float v) { return v >= 0.0f ? v : NEG * v; }

__device__ __forceinline__ unsigned short bfu(float f) {
    __hip_bfloat16 b = __float2bfloat16(f);   // RNE
    return *reinterpret_cast<unsigned short*>(&b);
}
__device__ __forceinline__ float ubf(unsigned short u) {
    return __uint_as_float(((unsigned int)u) << 16);
}

// ---------------- fused h = x@W (bf16 out) and alpha dots ----------------
__global__ __launch_bounds__(256) void gemm_k2(const float* __restrict__ X,
                                               const float* __restrict__ W,
                                               const float* __restrict__ a_src,
                                               const float* __restrict__ a_dst,
                                               unsigned short* __restrict__ Hb,
                                               float* __restrict__ as_,
                                               float4* __restrict__ nd) {
    __shared__ float xs[BM][132];
    const int tid  = threadIdx.x;
    const int tcol = tid & 31;
    const int trow = tid >> 5;
    const int row0 = blockIdx.x * BM;

    #pragma unroll
    for (int i = 0; i < 4; ++i) {
        const int l  = tid + 256 * i;
        const int r  = l >> 5;
        const int c4 = l & 31;
        float4 v = {0.f, 0.f, 0.f, 0.f};
        if (row0 + r < NN) v = ((const float4*)(X + (size_t)(row0 + r) * DD))[c4];
        *(float4*)&xs[r][c4 * 4] = v;
    }
    __syncthreads();

    const float4* __restrict__ W4 = (const float4*)W;
    float4 acc0 = {0,0,0,0}, acc1 = {0,0,0,0}, acc2 = {0,0,0,0}, acc3 = {0,0,0,0};

    for (int k = 0; k < DD; k += 4) {
        float4 wv0 = W4[(k + 0) * 32 + tcol];
        float4 wv1 = W4[(k + 1) * 32 + tcol];
        float4 wv2 = W4[(k + 2) * 32 + tcol];
        float4 wv3 = W4[(k + 3) * 32 + tcol];
        float4 xv0 = *(const float4*)&xs[4 * trow + 0][k];
        float4 xv1 = *(const float4*)&xs[4 * trow + 1][k];
        float4 xv2 = *(const float4*)&xs[4 * trow + 2][k];
        float4 xv3 = *(const float4*)&xs[4 * trow + 3][k];
        #define GSTEP(ACC, XV) \
            ACC.x += XV.x * wv0.x; ACC.y += XV.x * wv0.y; ACC.z += XV.x * wv0.z; ACC.w += XV.x * wv0.w; \
            ACC.x += XV.y * wv1.x; ACC.y += XV.y * wv1.y; ACC.z += XV.y * wv1.z; ACC.w += XV.y * wv1.w; \
            ACC.x += XV.z * wv2.x; ACC.y += XV.z * wv2.y; ACC.z += XV.z * wv2.z; ACC.w += XV.z * wv2.w; \
            ACC.x += XV.w * wv3.x; ACC.y += XV.w * wv3.y; ACC.z += XV.w * wv3.z; ACC.w += XV.w * wv3.w;
        GSTEP(acc0, xv0) GSTEP(acc1, xv1) GSTEP(acc2, xv2) GSTEP(acc3, xv3)
        #undef GSTEP
    }

    const float4 asv = ((const float4*)a_src)[tcol];
    const float4 adv = ((const float4*)a_dst)[tcol];
    float ps0 = acc0.x*asv.x + acc0.y*asv.y + acc0.z*asv.z + acc0.w*asv.w;
    float ps1 = acc1.x*asv.x + acc1.y*asv.y + acc1.z*asv.z + acc1.w*asv.w;
    float ps2 = acc2.x*asv.x + acc2.y*asv.y + acc2.z*asv.z + acc2.w*asv.w;
    float ps3 = acc3.x*asv.x + acc3.y*asv.y + acc3.z*asv.z + acc3.w*asv.w;
    float pd0 = acc0.x*adv.x + acc0.y*adv.y + acc0.z*adv.z + acc0.w*adv.w;
    float pd1 = acc1.x*adv.x + acc1.y*adv.y + acc1.z*adv.z + acc1.w*adv.w;
    float pd2 = acc2.x*adv.x + acc2.y*adv.y + acc2.z*adv.z + acc2.w*adv.w;
    float pd3 = acc3.x*adv.x + acc3.y*adv.y + acc3.z*adv.z + acc3.w*adv.w;
    #pragma unroll
    for (int off = 1; off < 8; off <<= 1) {
        ps0 += __shfl_xor(ps0, off); ps1 += __shfl_xor(ps1, off);
        ps2 += __shfl_xor(ps2, off); ps3 += __shfl_xor(ps3, off);
        pd0 += __shfl_xor(pd0, off); pd1 += __shfl_xor(pd1, off);
        pd2 += __shfl_xor(pd2, off); pd3 += __shfl_xor(pd3, off);
    }

    #pragma unroll
    for (int i = 0; i < 4; ++i) {
        const int row = row0 + 4 * trow + i;
        if (row >= NN) break;
        const float4 a = (i == 0) ? acc0 : (i == 1) ? acc1 : (i == 2) ? acc2 : acc3;
        ushort4 p;
        p.x = bfu(a.x); p.y = bfu(a.y); p.z = bfu(a.z); p.w = bfu(a.w);
        *(ushort4*)&Hb[(size_t)row * DD + 4 * tcol] = p;
    }
    if ((tcol & 7) == 0) {
        const int head = tcol >> 3;
        #pragma unroll
        for (int i = 0; i < 4; ++i) {
            const int row = row0 + 4 * trow + i;
            if (row >= NN) break;
            const float ps = (i == 0) ? ps0 : (i == 1) ? ps1 : (i == 2) ? ps2 : ps3;
            const float pd = (i == 0) ? pd0 : (i == 1) ? pd1 : (i == 2) ? pd2 : pd3;
            as_[(size_t)row * HH + head] = ps;
            ((float*)(nd + (size_t)row * 3))[head] = pd;
        }
    }
}

// ---------------- CSR build: two-level LDS counting sort ----------------
__global__ __launch_bounds__(256) void zero_k(int* __restrict__ p, int n) {
    const int i = blockIdx.x * 256 + threadIdx.x;
    if (i < n) p[i] = 0;
}

// pass 1: bucket edges by d>>8; one global fetch-add per (block,bucket)
__global__ __launch_bounds__(256) void p1_k(const int* __restrict__ ei,
                                            int* __restrict__ bcur,
                                            unsigned int* __restrict__ bkeys) {
    __shared__ int hist[NBUCK];
    __shared__ int cur[NBUCK];
    const int tid = threadIdx.x;
    const int e0 = blockIdx.x * P1CH;
    const int e1 = (e0 + P1CH < EE) ? e0 + P1CH : EE;

    for (int i = tid; i < NBUCK; i += 256) hist[i] = 0;
    __syncthreads();
    for (int e = e0 + tid; e < e1; e += 256)
        atomicAdd(&hist[ei[EE + e] >> 8], 1);
    __syncthreads();
    for (int i = tid; i < NBUCK; i += 256)
        cur[i] = (hist[i] > 0) ? atomicAdd(&bcur[i], hist[i]) : 0;
    __syncthreads();
    for (int e = e0 + tid; e < e1; e += 256) {
        const int s = ei[e];
        const int d = ei[EE + e];
        const int b = d >> 8;
        const int pos = atomicAdd(&cur[b], 1);
        if (pos < BUCKCAP)
            bkeys[(size_t)b * BUCKCAP + pos] = ((unsigned int)d << 16) | (unsigned int)s;
    }
}

// pass 2: one block per bucket; group by local node (d&255), write row_start/deg/csr
__global__ __launch_bounds__(256) void p2_k(const int* __restrict__ bcur,
                                            const unsigned int* __restrict__ bkeys,
                                            int* __restrict__ row_start,
                                            int* __restrict__ degA,
                                            unsigned short* __restrict__ csr) {
    __shared__ int hist[256];
    __shared__ int offs[256];
    __shared__ int cur[256];
    const int b = blockIdx.x;
    const int tid = threadIdx.x;
    int ne = bcur[b]; if (ne > BUCKCAP) ne = BUCKCAP;
    const unsigned int* keys = bkeys + (size_t)b * BUCKCAP;

    hist[tid] = 0;
    __syncthreads();
    for (int i = tid; i < ne; i += 256)
        atomicAdd(&hist[(keys[i] >> 16) & 255], 1);
    __syncthreads();
    const int v = hist[tid];
    offs[tid] = v;
    __syncthreads();
    for (int o = 1; o < 256; o <<= 1) {
        const int add = (tid >= o) ? offs[tid - o] : 0;
        __syncthreads();
        offs[tid] += add;
        __syncthreads();
    }
    const int excl = offs[tid] - v;
    const int n = (b << 8) + tid;
    if (n < NN) { row_start[n] = b * BUCKCAP + excl; degA[n] = v; }
    cur[tid] = excl;
    __syncthreads();
    for (int i = tid; i < ne; i += 256) {
        const unsigned int k = keys[i];
        const int local = (int)((k >> 16) & 255);
        const int pos = atomicAdd(&cur[local], 1);
        csr[(size_t)b * BUCKCAP + pos] = (unsigned short)(k & 0xFFFF);
    }
}

// ---------------- per-destination softmax stats + aggregation ----------------
// 8 nodes/block, 32 lanes/node, no __syncthreads. Writes nd slots 1,2 + xout.
__global__ __launch_bounds__(256) void node_k3(const int* __restrict__ row_start,
                                               const int* __restrict__ degA,
                                               const unsigned short* __restrict__ csr,
                                               const float* __restrict__ as_,
                                               float4* __restrict__ nd,    // [N][3]: ad, m, inv
                                               const unsigned short* __restrict__ Hb,
                                               const float* __restrict__ xprev,
                                               float* __restrict__ xout) {
    __shared__ int    src_l[NPB][CAPN];
    __shared__ float4 exp_l[NPB][CAPN];

    const int tid  = threadIdx.x;
    const int nl   = tid >> 5;
    const int lane = tid & 31;
    const int n    = blockIdx.x * NPB + nl;

    int deg = degA[n];
    if (deg > CAPN) deg = CAPN;
    const int row0 = row_start[n];

    if (deg == 0) {
        ((float4*)(xout + (size_t)n * DD))[lane] = ((const float4*)(xprev + (size_t)n * DD))[lane];
        return;
    }

    const float4 adv = nd[(size_t)n * 3];

    // Phase A: logits (stash), group max
    float4 mx = {-INFINITY, -INFINITY, -INFINITY, -INFINITY};
    for (int j = lane; j < deg; j += 32) {
        const int s = (int)csr[(size_t)row0 + j];
        const float4 av = *(const float4*)(as_ + (size_t)s * HH);
        float4 l;
        l.x = leaky(av.x + adv.x); l.y = leaky(av.y + adv.y);
        l.z = leaky(av.z + adv.z); l.w = leaky(av.w + adv.w);
        src_l[nl][j] = s; exp_l[nl][j] = l;
        mx.x = fmaxf(mx.x, l.x); mx.y = fmaxf(mx.y, l.y);
        mx.z = fmaxf(mx.z, l.z); mx.w = fmaxf(mx.w, l.w);
    }
    #pragma unroll
    for (int o = 1; o < 32; o <<= 1) {
        mx.x = fmaxf(mx.x, __shfl_xor(mx.x, o));
        mx.y = fmaxf(mx.y, __shfl_xor(mx.y, o));
        mx.z = fmaxf(mx.z, __shfl_xor(mx.z, o));
        mx.w = fmaxf(mx.w, __shfl_xor(mx.w, o));
    }

    // Phase B: exp (stash), group denom
    float4 ds = {0.f, 0.f, 0.f, 0.f};
    for (int j = lane; j < deg; j += 32) {
        const float4 l = exp_l[nl][j];
        float4 e4;
        e4.x = expf(l.x - mx.x); e4.y = expf(l.y - mx.y);
        e4.z = expf(l.z - mx.z); e4.w = expf(l.w - mx.w);
        exp_l[nl][j] = e4;
        ds.x += e4.x; ds.y += e4.y; ds.z += e4.z; ds.w += e4.w;
    }
    #pragma unroll
    for (int o = 1; o < 32; o <<= 1) {
        ds.x += __shfl_xor(ds.x, o); ds.y += __shfl_xor(ds.y, o);
        ds.z += __shfl_xor(ds.z, o); ds.w += __shfl_xor(ds.w, o);
    }
    float4 inv;
    inv.x = 1.0f / (ds.x + 1e-16f); inv.y = 1.0f / (ds.y + 1e-16f);
    inv.z = 1.0f / (ds.z + 1e-16f); inv.w = 1.0f / (ds.w + 1e-16f);

    if (lane == 0) {
        nd[(size_t)n * 3 + 1] = mx;
        nd[(size_t)n * 3 + 2] = inv;
    }

    // Phase C: aggregation — 2 edges/iter, 16 lanes/edge, 16B loads.
    const int esel = lane >> 4;
    const int sub  = lane & 15;
    const int hsel = sub >> 2;
    const float invh = (hsel == 0) ? inv.x : (hsel == 1) ? inv.y : (hsel == 2) ? inv.z : inv.w;
    float4 aclo = {0.f, 0.f, 0.f, 0.f};
    float4 achi = {0.f, 0.f, 0.f, 0.f};
    int j0 = 0;
    #pragma unroll 2
    for (; j0 + 2 <= deg; j0 += 2) {
        const int j = j0 + esel;
        const int s = src_l[nl][j];
        const float a = ((const float*)&exp_l[nl][j])[hsel] * invh;
        const ushort8v hv = *(const ushort8v*)&Hb[(size_t)s * DD + 8 * sub];
        aclo.x += ubf(hv[0]) * a; aclo.y += ubf(hv[1]) * a;
        aclo.z += ubf(hv[2]) * a; aclo.w += ubf(hv[3]) * a;
        achi.x += ubf(hv[4]) * a; achi.y += ubf(hv[5]) * a;
        achi.z += ubf(hv[6]) * a; achi.w += ubf(hv[7]) * a;
    }
    if (j0 < deg && esel == 0) {   // odd tail: esel==0 lanes only
        const int j = j0;
        const int s = src_l[nl][j];
        const float a = ((const float*)&exp_l[nl][j])[hsel] * invh;
        const ushort8v hv = *(const ushort8v*)&Hb[(size_t)s * DD + 8 * sub];
        aclo.x += ubf(hv[0]) * a; aclo.y += ubf(hv[1]) * a;
        aclo.z += ubf(hv[2]) * a; aclo.w += ubf(hv[3]) * a;
        achi.x += ubf(hv[4]) * a; achi.y += ubf(hv[5]) * a;
        achi.z += ubf(hv[6]) * a; achi.w += ubf(hv[7]) * a;
    }
    aclo.x += __shfl_xor(aclo.x, 16); aclo.y += __shfl_xor(aclo.y, 16);
    aclo.z += __shfl_xor(aclo.z, 16); aclo.w += __shfl_xor(aclo.w, 16);
    achi.x += __shfl_xor(achi.x, 16); achi.y += __shfl_xor(achi.y, 16);
    achi.z += __shfl_xor(achi.z, 16); achi.w += __shfl_xor(achi.w, 16);
    const float4 mine = (esel == 0) ? aclo : achi;
    const int fidx = 2 * sub + esel;
    const float4 xv = ((const float4*)(xprev + (size_t)n * DD))[fidx];
    float4 o;
    o.x = xv.x + mine.x; o.y = xv.y + mine.y; o.z = xv.z + mine.z; o.w = xv.w + mine.w;
    ((float4*)(xout + (size_t)n * DD))[fidx] = o;
}

// ---------------- edge-ordered rel + attn; one step per blockIdx.y ----------------
__global__ __launch_bounds__(256) void edgeattn3_k(const int* __restrict__ ei,
                                                   const float* __restrict__ as3,
                                                   const float4* __restrict__ nd3,
                                                   float* __restrict__ rel_out,
                                                   float* __restrict__ attn_out) {
    const int e = blockIdx.x * 256 + threadIdx.x;
    if (e >= EE) return;
    const int st = blockIdx.y;
    const int s = __builtin_nontemporal_load(ei + e);
    const int d = __builtin_nontemporal_load(ei + EE + e);
    const float4 av = *(const float4*)(as3 + ((size_t)st * NN + s) * HH);
    const float4* ndp = nd3 + ((size_t)st * NN + d) * 3;
    const float4 dv = ndp[0];
    const float4 mm = ndp[1];
    const float4 iv = ndp[2];
    float4v l;
    l.x = leaky(av.x + dv.x); l.y = leaky(av.y + dv.y);
    l.z = leaky(av.z + dv.z); l.w = leaky(av.w + dv.w);
    __builtin_nontemporal_store(l, (float4v*)(rel_out + ((size_t)st * EE + e) * HH));
    float4v a;
    a.x = expf(l.x - mm.x) * iv.x; a.y = expf(l.y - mm.y) * iv.y;
    a.z = expf(l.z - mm.z) * iv.z; a.w = expf(l.w - mm.w) * iv.w;
    __builtin_nontemporal_store(a, (float4v*)(attn_out + ((size_t)st * EE + e) * HH));
}

extern "C" void kernel_launch(void* const* d_in, const int* in_sizes, int n_in,
                              void* d_out, int out_size, void* d_ws, size_t ws_size,
                              hipStream_t stream) {
    const float* x     = (const float*)d_in[0];
    const int*   ei    = (const int*)d_in[1];
    const float* W     = (const float*)d_in[2];
    const float* a_src = (const float*)d_in[3];
    const float* a_dst = (const float*)d_in[4];

    float* xs_out   = (float*)d_out;                         // [3,N,128]
    float* attn_out = xs_out + (size_t)NSTEP * NN * DD;      // [3,E,4]
    float* rel_out  = attn_out + (size_t)NSTEP * EE * HH;    // [3,E,4]

    unsigned short* hb = (unsigned short*)d_ws;              // N*128 bf16          (12.8 MB)
    float*  as3   = (float*)(hb + (size_t)NN * DD);          // [3][N][4]           (2.4 MB)
    float4* nd3   = (float4*)(as3 + (size_t)NSTEP * NN * HH);// [3][N][3] ad,m,inv  (7.2 MB)
    int*    bcur  = (int*)(nd3 + (size_t)NSTEP * NN * 3);    // NBUCK               (~1 KB)
    unsigned int* bkeys = (unsigned int*)(bcur + NBUCK);     // NBUCK*BUCKCAP uint  (7.2 MB)
    int*    rowst = (int*)(bkeys + (size_t)NBUCK * BUCKCAP); // N                   (0.2 MB)
    int*    degA  = rowst + NN;                              // N                   (0.2 MB)
    unsigned short* csr = (unsigned short*)(degA + NN);      // NBUCK*BUCKCAP ushort(3.6 MB)

    // CSR build: two-level LDS counting sort (no per-edge global atomics)
    zero_k<<<1, 256, 0, stream>>>(bcur, NBUCK);
    p1_k<<<NB1, 256, 0, stream>>>(ei, bcur, bkeys);
    p2_k<<<NBUCK, 256, 0, stream>>>(bcur, bkeys, rowst, degA, csr);

    const float* xprev = x;
    for (int s = 0; s < NSTEP; ++s) {
        float* xs_s = xs_out + (size_t)s * NN * DD;
        float* as_  = as3 + (size_t)s * NN * HH;
        float4* nd  = nd3 + (size_t)s * NN * 3;

        gemm_k2<<<(NN + BM - 1) / BM, 256, 0, stream>>>(xprev, W, a_src, a_dst, hb, as_, nd);
        node_k3<<<NN / NPB, 256, 0, stream>>>(rowst, degA, csr, as_, nd, hb, xprev, xs_s);
        xprev = xs_s;
    }
    dim3 eg((EE + 255) / 256, NSTEP);
    edgeattn3_k<<<eg, 256, 0, stream>>>(ei, as3, nd3, rel_out, attn_out);
}